// Round 8
// baseline (367.437 us; speedup 1.0000x reference)
//
#include <hip/hip_runtime.h>
#include <hip/hip_bf16.h>

#define Bn 16
#define Sn 512
#define Hn 768
#define Ln 4096

typedef __attribute__((ext_vector_type(8))) short bf16x8;
typedef __attribute__((ext_vector_type(4))) float f32x4;

using bf16 = __hip_bfloat16;

constexpr int BL = 64;   // l-rows per block

// ---- LDS layout (time-multiplexed, offsets in bytes) ----
// phase2:  Xs dbuf: buf p @ p*32768, 512 rows x 64B (wave w owns rows w*128..+127)
//          (W-fragments are NOT staged: loaded global->reg, 2-ahead prefetch)
// softmax: redm[4][64] f32 @ 65536 (1024), reds[4][64] f32 @ 66560 (1024)
// phase4:  P [64 rows][1024 B] @ 0 (65536), chunks swizzled slot = chunk ^ (row&7)
// phase5:  P hoisted to regs, then XT dbuf in freed space: buf0 @ 0, buf1 @ 16384
constexpr int SM_BYTES  = 67584;  // 2 blocks/CU
constexpr int P_OFF     = 0;
constexpr int REDM_OFF  = 65536;
constexpr int REDS_OFF  = 66560;

typedef const __attribute__((address_space(1))) unsigned int* gas_ptr;
typedef __attribute__((address_space(3))) unsigned int* las_ptr;

__device__ __forceinline__ void gld_lds16(const void* g, void* l) {
  // async 16B/lane global->LDS DMA; LDS dest = wave-uniform base + lane*16
  __builtin_amdgcn_global_load_lds((gas_ptr)g, (las_ptr)l, 16, 0, 0);
}

__device__ __forceinline__ unsigned short bfbits(float x) {
  __hip_bfloat16 h = __float2bfloat16(x);
  unsigned short u;
  __builtin_memcpy(&u, &h, 2);
  return u;
}

union Pack8 { bf16 h[8]; uint4 u; };

__device__ inline uint4 cvt8(float4 a, float4 b) {
  Pack8 p;
  p.h[0] = __float2bfloat16(a.x); p.h[1] = __float2bfloat16(a.y);
  p.h[2] = __float2bfloat16(a.z); p.h[3] = __float2bfloat16(a.w);
  p.h[4] = __float2bfloat16(b.x); p.h[5] = __float2bfloat16(b.y);
  p.h[6] = __float2bfloat16(b.z); p.h[7] = __float2bfloat16(b.w);
  return p.u;
}

// ---- pre-kernel: X fp32 -> bf16 row-major AND bf16 transposed [B][H][S] ----
__global__ __launch_bounds__(256) void convert_x_kernel(
    const float* __restrict__ X, bf16* __restrict__ Xbf, bf16* __restrict__ XT) {
  __shared__ bf16 t[64][72];
  const int tid = threadIdx.x;
  const int b  = blockIdx.z;
  const int s0 = blockIdx.y * 64;
  const int h0 = blockIdx.x * 64;
  const int r = tid >> 2;
  const int p = tid & 3;
  const float* src = X + ((size_t)b * Sn + s0 + r) * Hn + h0 + p * 16;
  float4 a0 = *(const float4*)(src + 0);
  float4 a1 = *(const float4*)(src + 4);
  float4 a2 = *(const float4*)(src + 8);
  float4 a3 = *(const float4*)(src + 12);
  uint4 u0 = cvt8(a0, a1);
  uint4 u1 = cvt8(a2, a3);
  bf16* xb = Xbf + ((size_t)b * Sn + s0 + r) * Hn + h0 + p * 16;
  *(uint4*)(xb)     = u0;
  *(uint4*)(xb + 8) = u1;
  *(uint4*)&t[r][p * 16]     = u0;
  *(uint4*)&t[r][p * 16 + 8] = u1;
  __syncthreads();
  Pack8 o0, o1;
#pragma unroll
  for (int i = 0; i < 8; ++i) {
    o0.h[i] = t[p * 16 + i][r];
    o1.h[i] = t[p * 16 + 8 + i][r];
  }
  bf16* xt = XT + ((size_t)b * Hn + h0 + r) * Sn + s0 + p * 16;
  *(uint4*)(xt)     = o0.u;
  *(uint4*)(xt + 8) = o1.u;
}

// ---- pre-kernel: W fp32 -> bf16 ----
__global__ __launch_bounds__(256) void convert_w_kernel(
    const float* __restrict__ W, bf16* __restrict__ Wbf) {
  const size_t i = ((size_t)blockIdx.x * 256 + threadIdx.x) * 8;
  float4 a0 = *(const float4*)(W + i);
  float4 a1 = *(const float4*)(W + i + 4);
  *(uint4*)(Wbf + i) = cvt8(a0, a1);
}

// ---- fused main kernel (4 waves / 256 threads) ----
// phase2: wave w owns s-slice [w*128, w*128+128); tile M=64 x N=128.
//         BARRIER-FREE: Xs rows wave-private (self-staged), W-frags global->reg,
//         2-deep pipeline with counted vmcnt(12) -- waves drift independently.
// phase5: lg = w>>1 owns l rows lg*32..+31; sg = w&1 owns nt-parity of 128-h chunk
__global__ __launch_bounds__(256, 2) void attn_main_kernel(
    const int* __restrict__ masks,
    const bf16* __restrict__ Xbf, const bf16* __restrict__ XTg,
    const bf16* __restrict__ Wbf, float* __restrict__ out) {
  __shared__ char sm[SM_BYTES];
  const int tid  = threadIdx.x;
  const int w    = tid >> 6;
  const int lane = tid & 63;
  const int col  = lane & 15;
  const int quad = lane >> 4;
  const int lg   = w >> 1;
  const int sg   = w & 1;
  // XCD-aware swizzle: 1024 blocks = 8 XCDs x 128 (bijective).
  // Validated: FETCH 104.7 -> 63 MB.
  const int vb = (blockIdx.x & 7) * 128 + (blockIdx.x >> 3);
  const int b  = vb >> 6;
  const int l0 = (vb & 63) * BL;

  // mask bias -> 8 regs (this lane's 8 s-columns within the wave's 128-slice)
  float bias_r[8];
  {
    const int* mrow = masks + b * Sn + w * 128 + col;
#pragma unroll
    for (int nt = 0; nt < 8; ++nt)
      bias_r[nt] = mrow[nt * 16] ? 0.0f : -1e30f;
  }

  const f32x4 zero = {0.f, 0.f, 0.f, 0.f};
  f32x4 acc[4][8];
#pragma unroll
  for (int am = 0; am < 4; ++am)
#pragma unroll
    for (int nt = 0; nt < 8; ++nt) acc[am][nt] = zero;

  // ---- phase 2: scores[64l x 512s]; barrier-free per-wave pipeline ----
  // per k-step: 8 gld_lds16 (own Xs rows) + 4 dwordx4 (aF W-frags) = 12 VMEM ops.
  // 2-deep: iter n waits vmcnt(12) (iter n+1's 12 in flight), issues (n+2).
  {
    const int rr2 = lane >> 2;        // staging row within 16-row group
    const int cc2 = (lane & 3) * 8;   // staging k-offset (elements)
    const bf16* xsrc = Xbf + ((size_t)b * Sn + w * 128 + rr2) * Hn + cc2;
    const bf16* wbase = Wbf + ((size_t)(l0 + col)) * Hn + quad * 8;

    bf16x8 aFbuf[2][4];

#define LOAD_AF(P, N)                                                            \
    {                                                                            \
      _Pragma("unroll")                                                          \
      for (int am = 0; am < 4; ++am)                                             \
        aFbuf[P][am] = *(const bf16x8*)(wbase + (size_t)am * 16 * Hn + (N) * 32); \
    }

#define STAGE_XS(P, N)                                                           \
    {                                                                            \
      const bf16* g = xsrc + (N) * 32;                                           \
      char* d = sm + (P) * 32768 + (w * 128) * 64;                               \
      _Pragma("unroll")                                                          \
      for (int i = 0; i < 8; ++i) {                                              \
        gld_lds16(g, d);                                                         \
        g += 16 * Hn;                                                            \
        d += 1024;                                                               \
      }                                                                          \
    }

    LOAD_AF(0, 0); STAGE_XS(0, 0);
    LOAD_AF(1, 1); STAGE_XS(1, 1);

#pragma unroll
    for (int n = 0; n < 24; ++n) {
      const int p = n & 1;
      if (n < 23) {
        asm volatile("s_waitcnt vmcnt(12)" ::: "memory");  // (n)'s 12 landed; (n+1)'s in flight
      } else {
        asm volatile("s_waitcnt vmcnt(0)" ::: "memory");   // drain everything at the end
      }
      bf16x8 bF[8];
#pragma unroll
      for (int nt = 0; nt < 8; ++nt)
        bF[nt] = *(const bf16x8*)&sm[p * 32768 + (w * 128 + nt * 16 + col) * 64 + quad * 16];
      asm volatile("s_waitcnt lgkmcnt(0)" ::: "memory");   // reads retired -> buf p safe to overwrite
#pragma unroll
      for (int nt = 0; nt < 8; ++nt)
#pragma unroll
        for (int am = 0; am < 4; ++am)
          acc[am][nt] = __builtin_amdgcn_mfma_f32_16x16x32_bf16(aFbuf[p][am], bF[nt], acc[am][nt], 0, 0, 0);
      if (n < 22) {
        LOAD_AF(p, n + 2);   // aFbuf[p] dead after MFMA(n) -> reuse for n+2
        STAGE_XS(p, n + 2);  // buf p reads retired above -> DMA overwrite safe
      }
    }
#undef LOAD_AF
#undef STAGE_XS
  }

  // ---- phase 3: masked softmax, 4-way cross-wave combine over s-slices ----
  float* redm = (float*)&sm[REDM_OFF];
  float* reds = (float*)&sm[REDS_OFF];
  float mx[4][4];
#pragma unroll
  for (int am = 0; am < 4; ++am)
#pragma unroll
    for (int r = 0; r < 4; ++r) mx[am][r] = -3e38f;
#pragma unroll
  for (int am = 0; am < 4; ++am)
#pragma unroll
    for (int nt = 0; nt < 8; ++nt)
#pragma unroll
      for (int r = 0; r < 4; ++r) {
        acc[am][nt][r] += bias_r[nt];
        mx[am][r] = fmaxf(mx[am][r], acc[am][nt][r]);
      }
#pragma unroll
  for (int am = 0; am < 4; ++am)
#pragma unroll
    for (int r = 0; r < 4; ++r) {
      mx[am][r] = fmaxf(mx[am][r], __shfl_xor(mx[am][r], 1, 64));
      mx[am][r] = fmaxf(mx[am][r], __shfl_xor(mx[am][r], 2, 64));
      mx[am][r] = fmaxf(mx[am][r], __shfl_xor(mx[am][r], 4, 64));
      mx[am][r] = fmaxf(mx[am][r], __shfl_xor(mx[am][r], 8, 64));
    }
  if (col == 0) {
#pragma unroll
    for (int am = 0; am < 4; ++am)
#pragma unroll
      for (int r = 0; r < 4; ++r)
        redm[w * 64 + am * 16 + quad * 4 + r] = mx[am][r];
  }
  __syncthreads();
  float gmax[4][4], sum[4][4];
#pragma unroll
  for (int am = 0; am < 4; ++am)
#pragma unroll
    for (int r = 0; r < 4; ++r) {
      const int row = am * 16 + quad * 4 + r;
      gmax[am][r] = fmaxf(fmaxf(redm[row], redm[64 + row]),
                          fmaxf(redm[128 + row], redm[192 + row]));
      sum[am][r] = 0.f;
    }
#pragma unroll
  for (int am = 0; am < 4; ++am)
#pragma unroll
    for (int nt = 0; nt < 8; ++nt)
#pragma unroll
      for (int r = 0; r < 4; ++r) {
        const float e = __expf(acc[am][nt][r] - gmax[am][r]);
        acc[am][nt][r] = e;
        sum[am][r] += e;
      }
#pragma unroll
  for (int am = 0; am < 4; ++am)
#pragma unroll
    for (int r = 0; r < 4; ++r) {
      sum[am][r] += __shfl_xor(sum[am][r], 1, 64);
      sum[am][r] += __shfl_xor(sum[am][r], 2, 64);
      sum[am][r] += __shfl_xor(sum[am][r], 4, 64);
      sum[am][r] += __shfl_xor(sum[am][r], 8, 64);
    }
  if (col == 0) {
#pragma unroll
    for (int am = 0; am < 4; ++am)
#pragma unroll
      for (int r = 0; r < 4; ++r)
        reds[w * 64 + am * 16 + quad * 4 + r] = sum[am][r];
  }
  __syncthreads();
  float rs[4][4];
#pragma unroll
  for (int am = 0; am < 4; ++am)
#pragma unroll
    for (int r = 0; r < 4; ++r) {
      const int row = am * 16 + quad * 4 + r;
      rs[am][r] = 1.0f / (reds[row] + reds[64 + row] + reds[128 + row] + reds[192 + row]);
    }

  // ---- phase 4: P (unnormalized exp) -> LDS bf16, b32 packed via shfl pairing ----
  // P row = 1024 B (512 bf16). 16B chunk c of row stored at slot c ^ (row&7).
  // P overwrites the Xs buffers -- safe: all waves passed phase 3's first
  // syncthreads (phase 2 fully drained per-wave by its final vmcnt(0)).
  const int pi = col & 1;  // parity
#pragma unroll
  for (int am = 0; am < 4; ++am)
#pragma unroll
    for (int t = 0; t < 4; ++t)
#pragma unroll
      for (int r = 0; r < 4; ++r) {
        const float own0 = acc[am][2 * t][r];
        const float own1 = acc[am][2 * t + 1][r];
        const float p0 = __shfl_xor(own0, 1, 64);
        const float p1 = __shfl_xor(own1, 1, 64);
        const float lo = pi ? p1 : own0;
        const float hi = pi ? own1 : p0;
        const unsigned pk = (unsigned)bfbits(lo) | ((unsigned)bfbits(hi) << 16);
        const int nt_w = 2 * t + pi;
        const int row = am * 16 + quad * 4 + r;
        const int sp = w * 128 + nt_w * 16 + (col & ~1);
        const int slot = (sp >> 3) ^ (row & 7);
        *(unsigned*)&sm[P_OFF + row * 1024 + slot * 16 + (sp & 7) * 2] = pk;
      }

  __syncthreads();  // P fully written, visible to all waves

  // ---- phase 5 pre: hoist this wave's P fragments to registers (read ONCE) ----
  bf16x8 preg[2][16];
#pragma unroll
  for (int a = 0; a < 2; ++a) {
    const int row = lg * 32 + a * 16 + col;
#pragma unroll
    for (int kf = 0; kf < 16; ++kf) {
      const int slot = (kf * 4 + quad) ^ (row & 7);
      preg[a][kf] = *(const bf16x8*)&sm[P_OFF + row * 1024 + slot * 16];
    }
  }
  __syncthreads();  // all hoists complete; P region now free for XT dbuf

  // ---- phase 5: O[64l x 768h] = P(regs) x XT(LDS dbuf @0/@16384) ----
  const int rr5 = lane >> 3;
  const int cc5 = lane & 7;
  auto stage_xt = [&](int bufoff, int n0, int s0) {
    // chunk swizzle at the SOURCE: lane (rr,cc) fetches s-chunk cc^rr so that
    // row rr's chunk c lands at LDS slot c^rr.
    const int r0 = w * 32;
    const bf16* g = XTg + ((size_t)b * Hn + n0 * 128 + r0 + rr5) * Sn + s0 + (cc5 ^ rr5) * 8;
#pragma unroll
    for (int i = 0; i < 4; ++i) {
      gld_lds16(g, &sm[bufoff + (r0 + i * 8) * 128]);
      g += 8 * Sn;
    }
  };

  stage_xt(0, 0, 0);
  asm volatile("s_waitcnt vmcnt(0)" ::: "memory");
  __builtin_amdgcn_s_barrier();

  for (int n0 = 0; n0 < Hn / 128; ++n0) {
    f32x4 oacc[2][4];
#pragma unroll
    for (int a = 0; a < 2; ++a)
#pragma unroll
      for (int nt = 0; nt < 4; ++nt) oacc[a][nt] = zero;
#pragma unroll
    for (int s0i = 0; s0i < 8; ++s0i) {
      const int par = s0i & 1;
      // prefetch next tile into the other buffer BEFORE compute (hidden by MFMAs)
      if (s0i < 7)           stage_xt((par ^ 1) * 16384, n0, (s0i + 1) * 64);
      else if (n0 < Hn / 128 - 1) stage_xt((par ^ 1) * 16384, n0 + 1, 0);
#pragma unroll
      for (int ks = 0; ks < 2; ++ks) {
        const int kf = s0i * 2 + ks;
        const bf16x8 pa0 = preg[0][kf];
        const bf16x8 pa1 = preg[1][kf];
#pragma unroll
        for (int nt = 0; nt < 4; ++nt) {
          const int hl = (nt * 2 + sg) * 16 + col;
          const int xslot = (ks * 4 + quad) ^ (hl & 7);
          bf16x8 xb = *(const bf16x8*)&sm[par * 16384 + hl * 128 + xslot * 16];
          oacc[0][nt] = __builtin_amdgcn_mfma_f32_16x16x32_bf16(pa0, xb, oacc[0][nt], 0, 0, 0);
          oacc[1][nt] = __builtin_amdgcn_mfma_f32_16x16x32_bf16(pa1, xb, oacc[1][nt], 0, 0, 0);
        }
      }
      asm volatile("s_waitcnt vmcnt(0)" ::: "memory");  // prefetch (issued pre-compute) landed
      __builtin_amdgcn_s_barrier();                     // next buffer published
    }
#pragma unroll
    for (int a = 0; a < 2; ++a)
#pragma unroll
      for (int nt = 0; nt < 4; ++nt) {
        const int h = n0 * 128 + (nt * 2 + sg) * 16 + col;
        const int lbase = l0 + lg * 32 + a * 16 + quad * 4;
#pragma unroll
        for (int r = 0; r < 4; ++r)
          out[((size_t)b * Ln + lbase + r) * Hn + h] = oacc[a][nt][r] * rs[lg * 2 + a][r];
      }
  }
}

// ---- fallback (ws too small): fp32 wave-per-(b,l), slow but correct ----
__global__ __launch_bounds__(256) void attn_fallback_kernel(
    const float* __restrict__ X, const int* __restrict__ masks,
    const float* __restrict__ W, float* __restrict__ out) {
  __shared__ float sc[4][Sn];
  const int wv = threadIdx.x >> 6, lane = threadIdx.x & 63;
  const int gw = blockIdx.x * 4 + wv;
  const int b = gw / Ln, l = gw % Ln;
  float wreg[12];
#pragma unroll
  for (int j = 0; j < 12; ++j) wreg[j] = W[(size_t)l * Hn + j * 64 + lane];
  for (int s = 0; s < Sn; ++s) {
    const float* xr = X + ((size_t)b * Sn + s) * Hn;
    float p = 0.f;
#pragma unroll
    for (int j = 0; j < 12; ++j) p += xr[j * 64 + lane] * wreg[j];
#pragma unroll
    for (int off = 32; off > 0; off >>= 1) p += __shfl_xor(p, off, 64);
    if (lane == 0) sc[wv][s] = p;
  }
  __syncthreads();
  float m = -3e38f;
#pragma unroll
  for (int i = 0; i < 8; ++i) {
    const int s = lane * 8 + i;
    const float v = sc[wv][s] + (masks[b * Sn + s] ? 0.f : -1e30f);
    sc[wv][s] = v;
    m = fmaxf(m, v);
  }
#pragma unroll
  for (int off = 32; off > 0; off >>= 1) m = fmaxf(m, __shfl_xor(m, off, 64));
  __syncthreads();
  float sum = 0.f;
#pragma unroll
  for (int i = 0; i < 8; ++i) {
    const int s = lane * 8 + i;
    const float e = __expf(sc[wv][s] - m);
    sc[wv][s] = e;
    sum += e;
  }
#pragma unroll
  for (int off = 32; off > 0; off >>= 1) sum += __shfl_xor(sum, off, 64);
  const float rs = 1.0f / sum;
  __syncthreads();
  float o[12];
#pragma unroll
  for (int j = 0; j < 12; ++j) o[j] = 0.f;
  for (int s = 0; s < Sn; ++s) {
    const float p = sc[wv][s];
    const float* xr = X + ((size_t)b * Sn + s) * Hn;
#pragma unroll
    for (int j = 0; j < 12; ++j) o[j] += p * xr[j * 64 + lane];
  }
#pragma unroll
  for (int j = 0; j < 12; ++j)
    out[((size_t)b * Ln + l) * Hn + j * 64 + lane] = o[j] * rs;
}

extern "C" void kernel_launch(void* const* d_in, const int* in_sizes, int n_in,
                              void* d_out, int out_size, void* d_ws, size_t ws_size,
                              hipStream_t stream) {
  const float* X     = (const float*)d_in[0];
  const int*   masks = (const int*)d_in[1];
  const float* W     = (const float*)d_in[2];
  float* out = (float*)d_out;

  const size_t need = ((size_t)2 * Bn * Sn * Hn + (size_t)Ln * Hn) * sizeof(bf16);
  if (ws_size >= need) {
    bf16* Xbf = (bf16*)d_ws;
    bf16* XT  = Xbf + (size_t)Bn * Sn * Hn;
    bf16* Wbf = XT  + (size_t)Bn * Sn * Hn;
    convert_x_kernel<<<dim3(Hn / 64, Sn / 64, Bn), 256, 0, stream>>>(X, Xbf, XT);
    convert_w_kernel<<<dim3((Ln * Hn) / 2048), 256, 0, stream>>>(W, Wbf);
    attn_main_kernel<<<dim3(Bn * (Ln / BL)), 256, 0, stream>>>(masks, Xbf, XT, Wbf, out);
  } else {
    attn_fallback_kernel<<<dim3(Bn * Ln / 4), 256, 0, stream>>>(X, masks, W, out);
  }
}